// Round 1
// baseline (1043.181 us; speedup 1.0000x reference)
//
#include <hip/hip_runtime.h>
#include <hip/hip_bf16.h>
#include <stddef.h>

// Sizes (fixed by the problem)
// N=4, C=64, F=256, T=256, B=N*F=1024, D=128, H=32, 4H=128, NG=384

__device__ __forceinline__ float fsig(float x) {
    return __builtin_amdgcn_rcpf(1.f + __expf(-x));
}
__device__ __forceinline__ float ftanh(float x) {
    return 1.f - 2.f * __builtin_amdgcn_rcpf(__expf(2.f * x) + 1.f);
}
__device__ __forceinline__ float wredsum(float v) {   // 64-lane sum
#pragma unroll
    for (int off = 32; off; off >>= 1) v += __shfl_xor(v, off);
    return v;
}
__device__ __forceinline__ float wredmax(float v) {   // 64-lane max
#pragma unroll
    for (int off = 32; off; off >>= 1) v = fmaxf(v, __shfl_xor(v, off));
    return v;
}
__device__ __forceinline__ float hredsum(float v) {   // 32-lane-group sum
#pragma unroll
    for (int off = 16; off; off >>= 1) v += __shfl_xor(v, off);
    return v;
}

// ---------------------------------------------------------------------------
// Kernel 1: inputs [N,C,F,T,2] -> xn [B,T,128] with LN1 fused.
// block = (tc, f, n); 256 threads; t-chunk = 32
// ---------------------------------------------------------------------------
__global__ __launch_bounds__(256) void k_prep(const float* __restrict__ in,
                                              const float* __restrict__ g1,
                                              const float* __restrict__ b1,
                                              float* __restrict__ xn) {
    __shared__ float xl[32][129];
    const int n = blockIdx.z, f = blockIdx.y, t0 = blockIdx.x * 32;
    const int tid = threadIdx.x;
    const int c = tid >> 2, q = tid & 3;
    const float* src = in + ((size_t)(n * 64 + c) * 256 + f) * 512 + t0 * 2 + q * 16;
#pragma unroll
    for (int e = 0; e < 4; ++e) {
        float4 v4 = *(const float4*)(src + e * 4);
        int dt = q * 8 + e * 2;           // k0 = q*16+e*4 (even); dt = k0/2
        xl[dt][c]          = v4.x;        // ri=0
        xl[dt][c + 64]     = v4.y;        // ri=1
        xl[dt + 1][c]      = v4.z;
        xl[dt + 1][c + 64] = v4.w;
    }
    __syncthreads();
    const int lane = tid & 63, w = tid >> 6;
    const int b = n * 256 + f;
#pragma unroll 1
    for (int r = 0; r < 8; ++r) {
        int dt = w * 8 + r;
        float a = xl[dt][lane], bb = xl[dt][lane + 64];
        float s = wredsum(a + bb);
        float mean = s * 0.0078125f;               // /128
        float da = a - mean, db = bb - mean;
        float var = wredsum(da * da + db * db) * 0.0078125f;
        float inv = __builtin_amdgcn_rsqf(var + 1e-5f);
        size_t base = ((size_t)b * 256 + (t0 + dt)) * 128;
        xn[base + lane]      = da * inv * g1[lane] + b1[lane];
        xn[base + lane + 64] = db * inv * g1[lane + 64] + b1[lane + 64];
    }
}

// ---------------------------------------------------------------------------
// Kernel 2: gx[M,384] = xn[M,128] @ Wcatᵀ + (bih+bhh).  M = 262144.
// Tile 128(M) x 64(N), K staged in 2 phases of 64. blockIdx.y: l*2+half
// ---------------------------------------------------------------------------
__global__ __launch_bounds__(256) void k_gemm(const float* __restrict__ xn,
                                              const float* __restrict__ Wq,
                                              const float* __restrict__ Wk,
                                              const float* __restrict__ Wv,
                                              const float* __restrict__ bihq, const float* __restrict__ bhhq,
                                              const float* __restrict__ bihk, const float* __restrict__ bhhk,
                                              const float* __restrict__ bihv, const float* __restrict__ bhhv,
                                              float* __restrict__ gx) {
    __shared__ float a_lds[64][136];   // [k][m], m-pad to 136 (16B-aligned stride)
    __shared__ float w_lds[64][68];    // [k][n]
    const int tid = threadIdx.x;
    const int m0 = blockIdx.x * 128;
    const int yb = blockIdx.y;
    const int l = yb >> 1, n0 = (yb & 1) * 64;
    const float* W   = (l == 0) ? Wq   : (l == 1) ? Wk   : Wv;
    const float* bih = (l == 0) ? bihq : (l == 1) ? bihk : bihv;
    const float* bhh = (l == 0) ? bhhq : (l == 1) ? bhhk : bhhv;
    float acc[8][4];
#pragma unroll
    for (int i = 0; i < 8; ++i)
#pragma unroll
        for (int j = 0; j < 4; ++j) acc[i][j] = 0.f;
    const int tidn = tid & 15, tidm = tid >> 4;

    for (int kp = 0; kp < 2; ++kp) {
        {   // stage A: 128 rows x 64 k
            int row = tid >> 1, hq = tid & 1;
            const float* srcA = xn + (size_t)(m0 + row) * 128 + kp * 64 + hq * 32;
#pragma unroll
            for (int e = 0; e < 8; ++e) {
                float4 v4 = *(const float4*)(srcA + e * 4);
                int kl = hq * 32 + e * 4;
                a_lds[kl][row] = v4.x; a_lds[kl + 1][row] = v4.y;
                a_lds[kl + 2][row] = v4.z; a_lds[kl + 3][row] = v4.w;
            }
            // stage W: 64 n-rows x 64 k
            int nr = tid >> 2, qq = tid & 3;
            const float* srcW = W + (size_t)(n0 + nr) * 128 + kp * 64 + qq * 16;
#pragma unroll
            for (int e = 0; e < 4; ++e) {
                float4 v4 = *(const float4*)(srcW + e * 4);
                int kl = qq * 16 + e * 4;
                w_lds[kl][nr] = v4.x; w_lds[kl + 1][nr] = v4.y;
                w_lds[kl + 2][nr] = v4.z; w_lds[kl + 3][nr] = v4.w;
            }
        }
        __syncthreads();
#pragma unroll 8
        for (int kl = 0; kl < 64; ++kl) {
            float4 a0 = *(const float4*)&a_lds[kl][tidm * 8];
            float4 a1 = *(const float4*)&a_lds[kl][tidm * 8 + 4];
            float4 w4 = *(const float4*)&w_lds[kl][tidn * 4];
            float av[8] = {a0.x, a0.y, a0.z, a0.w, a1.x, a1.y, a1.z, a1.w};
            float wv[4] = {w4.x, w4.y, w4.z, w4.w};
#pragma unroll
            for (int i = 0; i < 8; ++i)
#pragma unroll
                for (int j = 0; j < 4; ++j) acc[i][j] += av[i] * wv[j];
        }
        __syncthreads();
    }
    const int ngl = n0 + tidn * 4;   // gate index within this lstm's 128
    float4 bs;
    bs.x = bih[ngl] + bhh[ngl];
    bs.y = bih[ngl + 1] + bhh[ngl + 1];
    bs.z = bih[ngl + 2] + bhh[ngl + 2];
    bs.w = bih[ngl + 3] + bhh[ngl + 3];
#pragma unroll
    for (int i = 0; i < 8; ++i) {
        size_t m = (size_t)m0 + tidm * 8 + i;
        float4 o;
        o.x = acc[i][0] + bs.x; o.y = acc[i][1] + bs.y;
        o.z = acc[i][2] + bs.z; o.w = acc[i][3] + bs.w;
        *(float4*)&gx[m * 384 + l * 128 + ngl] = o;
    }
}

// ---------------------------------------------------------------------------
// Kernel 3: LSTM recurrence. One wave per (lstm l, batch b) sequence.
// gates already have x@Wihᵀ + bias in gx; add h@Whhᵀ each step.
// ---------------------------------------------------------------------------
__global__ __launch_bounds__(256) void k_lstm(const float* __restrict__ gx,
                                              const float* __restrict__ Whq,
                                              const float* __restrict__ Whk,
                                              const float* __restrict__ Whv,
                                              float* __restrict__ qkv) {
    __shared__ float hbuf[4][32];
    __shared__ float gbuf[4][128];
    const int tid = threadIdx.x, w = tid >> 6, lane = tid & 63;
    const int sid = blockIdx.x * 4 + w;        // 0..3071
    const int l = sid >> 10, b = sid & 1023;
    const float* Wh = (l == 0) ? Whq : (l == 1) ? Whk : Whv;
    float w0[32], w1[32];
    {
        const float4* r0 = (const float4*)(Wh + (size_t)(2 * lane) * 32);
        const float4* r1 = (const float4*)(Wh + (size_t)(2 * lane + 1) * 32);
#pragma unroll
        for (int e = 0; e < 8; ++e) {
            float4 a = r0[e];
            w0[4 * e] = a.x; w0[4 * e + 1] = a.y; w0[4 * e + 2] = a.z; w0[4 * e + 3] = a.w;
            float4 c4 = r1[e];
            w1[4 * e] = c4.x; w1[4 * e + 1] = c4.y; w1[4 * e + 2] = c4.z; w1[4 * e + 3] = c4.w;
        }
    }
    if (lane < 32) hbuf[w][lane] = 0.f;
    float c = 0.f;
    const float* gp = gx + (size_t)b * 98304 + l * 128 + 2 * lane;  // 98304 = 256*384
    float* outp = qkv + (size_t)sid * 8192;                          // 8192 = 256*32
    float2 gc  = *(const float2*)gp;
    float2 g1v = *(const float2*)(gp + 384);
    for (int t = 0; t < 256; ++t) {
        float2 g2v = make_float2(0.f, 0.f);
        if (t + 2 < 256) g2v = *(const float2*)(gp + (size_t)(t + 2) * 384);
        float p0 = 0.f, p1 = 0.f, q0 = 0.f, q1 = 0.f;
#pragma unroll
        for (int jj = 0; jj < 8; ++jj) {
            float4 h4 = *(const float4*)&hbuf[w][jj * 4];
            if (jj & 1) {
                p1 += w0[4 * jj] * h4.x; p1 += w0[4 * jj + 1] * h4.y;
                p1 += w0[4 * jj + 2] * h4.z; p1 += w0[4 * jj + 3] * h4.w;
                q1 += w1[4 * jj] * h4.x; q1 += w1[4 * jj + 1] * h4.y;
                q1 += w1[4 * jj + 2] * h4.z; q1 += w1[4 * jj + 3] * h4.w;
            } else {
                p0 += w0[4 * jj] * h4.x; p0 += w0[4 * jj + 1] * h4.y;
                p0 += w0[4 * jj + 2] * h4.z; p0 += w0[4 * jj + 3] * h4.w;
                q0 += w1[4 * jj] * h4.x; q0 += w1[4 * jj + 1] * h4.y;
                q0 += w1[4 * jj + 2] * h4.z; q0 += w1[4 * jj + 3] * h4.w;
            }
        }
        float g0 = gc.x + p0 + p1;
        float g1 = gc.y + q0 + q1;
        *(float2*)&gbuf[w][2 * lane] = make_float2(g0, g1);
        if (lane < 32) {
            float gi = gbuf[w][lane];
            float gf = gbuf[w][lane + 32];
            float gg = gbuf[w][lane + 64];
            float go = gbuf[w][lane + 96];
            c = fsig(gf) * c + fsig(gi) * ftanh(gg);
            float hN = fsig(go) * ftanh(c);
            hbuf[w][lane] = hN;
            outp[(size_t)t * 32 + lane] = hN;
        }
        gc = g1v; g1v = g2v;
    }
}

// ---------------------------------------------------------------------------
// Kernel 4: attention. block per b; K in LDS (padded), V via L1/L2,
// 2 query rows per wave (t and t+128). Multiplicative tril mask semantics.
// ---------------------------------------------------------------------------
__global__ __launch_bounds__(256) void k_attn(const float* __restrict__ qkv,
                                              float* __restrict__ wvout) {
    __shared__ float k_lds[256][33];
    __shared__ float attn_s[4][2][256];
    const int tid = threadIdx.x, w = tid >> 6, lane = tid & 63;
    const int b = blockIdx.x;
    const float* qb = qkv;
    const float* kb = qkv + 8388608;     // B*T*32
    const float* vb = qkv + 16777216;
    for (int idx = tid; idx < 8192; idx += 256) {
        int s = idx >> 5, j = idx & 31;
        k_lds[s][j] = kb[(size_t)b * 8192 + idx];
    }
    __syncthreads();
    const int jj = lane & 31, half = lane >> 5;
    const float* vrow = vb + (size_t)b * 8192;
    for (int i = 0; i < 32; ++i) {
        const int tA = w + i * 4;       // 0..127
        const int tB = tA + 128;        // 128..255
        float qa[32], qc[32];
        const float4* qAp = (const float4*)(qb + ((size_t)b * 256 + tA) * 32);
        const float4* qBp = (const float4*)(qb + ((size_t)b * 256 + tB) * 32);
#pragma unroll
        for (int e = 0; e < 8; ++e) {
            float4 x4 = qAp[e];
            qa[4 * e] = x4.x; qa[4 * e + 1] = x4.y; qa[4 * e + 2] = x4.z; qa[4 * e + 3] = x4.w;
            float4 y4 = qBp[e];
            qc[4 * e] = y4.x; qc[4 * e + 1] = y4.y; qc[4 * e + 2] = y4.z; qc[4 * e + 3] = y4.w;
        }
        float eA[4] = {0, 0, 0, 0}, eB[4] = {0, 0, 0, 0};
#pragma unroll
        for (int j = 0; j < 32; ++j) {
            float qaj = qa[j], qcj = qc[j];
#pragma unroll
            for (int m = 0; m < 4; ++m) {
                float kv = k_lds[lane + (m << 6)][j];
                eA[m] += qaj * kv;
                eB[m] += qcj * kv;
            }
        }
        float mA = -1e30f, mB = -1e30f;
#pragma unroll
        for (int m = 0; m < 4; ++m) {
            int s = lane + (m << 6);
            eA[m] = (s <= tA) ? eA[m] * 0.25f : 0.f;   // multiplicative mask -> exact 0
            eB[m] = (s <= tB) ? eB[m] * 0.25f : 0.f;
            mA = fmaxf(mA, eA[m]); mB = fmaxf(mB, eB[m]);
        }
        mA = wredmax(mA); mB = wredmax(mB);
        float sA = 0.f, sB = 0.f, pA[4], pB[4];
#pragma unroll
        for (int m = 0; m < 4; ++m) {
            pA[m] = __expf(eA[m] - mA); sA += pA[m];
            pB[m] = __expf(eB[m] - mB); sB += pB[m];
        }
        sA = wredsum(sA); sB = wredsum(sB);
        float rA = __builtin_amdgcn_rcpf(sA), rB = __builtin_amdgcn_rcpf(sB);
#pragma unroll
        for (int m = 0; m < 4; ++m) {
            attn_s[w][0][lane + (m << 6)] = pA[m] * rA;
            attn_s[w][1][lane + (m << 6)] = pB[m] * rB;
        }
        float aAx = 0, aAy = 0, aAz = 0, aAw = 0;
        float aBx = 0, aBy = 0, aBz = 0, aBw = 0;
#pragma unroll 4
        for (int s4 = 0; s4 < 32; ++s4) {
            int s0 = (half << 7) + (s4 << 2);
            float4 a4 = *(const float4*)&attn_s[w][0][s0];
            float4 c4 = *(const float4*)&attn_s[w][1][s0];
            float v0 = vrow[(size_t)s0 * 32 + jj];
            float v1 = vrow[(size_t)(s0 + 1) * 32 + jj];
            float v2 = vrow[(size_t)(s0 + 2) * 32 + jj];
            float v3 = vrow[(size_t)(s0 + 3) * 32 + jj];
            aAx += a4.x * v0; aAy += a4.y * v1; aAz += a4.z * v2; aAw += a4.w * v3;
            aBx += c4.x * v0; aBy += c4.y * v1; aBz += c4.z * v2; aBw += c4.w * v3;
        }
        float accA = (aAx + aAy) + (aAz + aAw);
        float accB = (aBx + aBy) + (aBz + aBw);
        accA += __shfl_down(accA, 32);
        accB += __shfl_down(accB, 32);
        if (lane < 32) {
            wvout[((size_t)b * 256 + tA) * 32 + lane] = accA;
            wvout[((size_t)b * 256 + tB) * 32 + lane] = accB;
        }
    }
}

// ---------------------------------------------------------------------------
// Kernel 5: LN2 + complex linear + LN3 + PReLU + residual + scatter-store.
// block = (tc, f, n); 256 threads; t-chunk = 32
// ---------------------------------------------------------------------------
__global__ __launch_bounds__(256) void k_post(const float* __restrict__ wv,
                                              const float* __restrict__ in,
                                              const float* __restrict__ g2,
                                              const float* __restrict__ b2,
                                              const float* __restrict__ Wr,
                                              const float* __restrict__ br,
                                              const float* __restrict__ Wi,
                                              const float* __restrict__ bi,
                                              const float* __restrict__ g3,
                                              const float* __restrict__ b3,
                                              const float* __restrict__ pa,
                                              float* __restrict__ outp) {
    __shared__ float xv[32][33];
    __shared__ float wr_l[64][17], wi_l[64][17];
    __shared__ float out_s[64][65];
    const int tid = threadIdx.x;
    const int n = blockIdx.z, f = blockIdx.y, t0 = blockIdx.x * 32;
    const int b = n * 256 + f;
    for (int idx = tid; idx < 1024; idx += 256) {
        int dt = idx >> 5, j = idx & 31;
        xv[dt][j] = wv[((size_t)b * 256 + t0 + dt) * 32 + j];
        int cc = idx >> 4, jjj = idx & 15;
        wr_l[cc][jjj] = Wr[idx];
        wi_l[cc][jjj] = Wi[idx];
    }
    __syncthreads();
    const int lane = tid & 63, w = tid >> 6;
    // LN2 over 32 per row; each 32-lane half does one row
#pragma unroll 1
    for (int r = 0; r < 4; ++r) {
        int dt = w * 8 + r * 2 + (lane >> 5);
        int j = lane & 31;
        float v = xv[dt][j];
        float mean = hredsum(v) * 0.03125f;
        float d = v - mean;
        float var = hredsum(d * d) * 0.03125f;
        float inv = __builtin_amdgcn_rsqf(var + 1e-5f);
        xv[dt][j] = d * inv * g2[j] + b2[j];
    }
    __syncthreads();
    const int c = lane;
    const float g3c = g3[c], b3c = b3[c];
    const float bd = br[c] - bi[c], bsum = br[c] + bi[c];
    const float alpha = pa[0];
#pragma unroll 1
    for (int r = 0; r < 8; ++r) {
        int dt = w * 8 + r;
        float re = 0.f, im = 0.f;
#pragma unroll
        for (int j = 0; j < 16; ++j) {
            float xr = xv[dt][j], xi2 = xv[dt][16 + j];
            float wrv = wr_l[c][j], wiv = wi_l[c][j];
            re += xr * wrv; re -= xi2 * wiv;
            im += xi2 * wrv; im += xr * wiv;
        }
        re += bd; im += bsum;
        // LN3 over c (the 64 lanes), separately for real and imag
        float mR = wredsum(re) * 0.015625f;
        float dR = re - mR;
        float vR = wredsum(dR * dR) * 0.015625f;
        float nR = dR * __builtin_amdgcn_rsqf(vR + 1e-5f) * g3c + b3c;
        nR = (nR >= 0.f) ? nR : alpha * nR;
        float mI = wredsum(im) * 0.015625f;
        float dI = im - mI;
        float vI = wredsum(dI * dI) * 0.015625f;
        float nI = dI * __builtin_amdgcn_rsqf(vI + 1e-5f) * g3c + b3c;
        nI = (nI >= 0.f) ? nI : alpha * nI;
        out_s[c][dt * 2]     = nR;
        out_s[c][dt * 2 + 1] = nI;
    }
    __syncthreads();
    // residual + coalesced store in input layout
    const int cc = tid >> 2, q = tid & 3;
    size_t base = ((size_t)(n * 64 + cc) * 256 + f) * 512 + t0 * 2 + q * 16;
#pragma unroll
    for (int e = 0; e < 4; ++e) {
        float4 iv = *(const float4*)(in + base + e * 4);
        int k0 = q * 16 + e * 4;
        float4 ov;
        ov.x = out_s[cc][k0]     + iv.x;
        ov.y = out_s[cc][k0 + 1] + iv.y;
        ov.z = out_s[cc][k0 + 2] + iv.z;
        ov.w = out_s[cc][k0 + 3] + iv.w;
        *(float4*)(outp + base + e * 4) = ov;
    }
}

// ---------------------------------------------------------------------------
extern "C" void kernel_launch(void* const* d_in, const int* in_sizes, int n_in,
                              void* d_out, int out_size, void* d_ws, size_t ws_size,
                              hipStream_t stream) {
    const float* in   = (const float*)d_in[0];
    const float* g1   = (const float*)d_in[1];
    const float* b1   = (const float*)d_in[2];
    const float* Wq   = (const float*)d_in[3];
    const float* Whq  = (const float*)d_in[4];
    const float* bihq = (const float*)d_in[5];
    const float* bhhq = (const float*)d_in[6];
    const float* Wk   = (const float*)d_in[7];
    const float* Whk  = (const float*)d_in[8];
    const float* bihk = (const float*)d_in[9];
    const float* bhhk = (const float*)d_in[10];
    const float* Wv   = (const float*)d_in[11];
    const float* Whv  = (const float*)d_in[12];
    const float* bihv = (const float*)d_in[13];
    const float* bhhv = (const float*)d_in[14];
    const float* g2   = (const float*)d_in[15];
    const float* b2   = (const float*)d_in[16];
    const float* Wr   = (const float*)d_in[17];
    const float* br   = (const float*)d_in[18];
    const float* Wi   = (const float*)d_in[19];
    const float* bi   = (const float*)d_in[20];
    const float* g3   = (const float*)d_in[21];
    const float* b3   = (const float*)d_in[22];
    const float* pa   = (const float*)d_in[23];
    float* outp = (float*)d_out;

    // workspace layout (bytes): [0, 384MiB) gx ; [384MiB, 512MiB) xn, later q/k/v/wv
    float* gxb  = (float*)d_ws;
    float* reg2 = gxb + 100663296;         // 262144*384
    float* xn   = reg2;
    float* qkv  = reg2;                    // q | k | v, each 262144*32
    float* wvb  = reg2 + 25165824;         // 3 * 8388608

    k_prep<<<dim3(8, 256, 4), dim3(256), 0, stream>>>(in, g1, b1, xn);
    k_gemm<<<dim3(2048, 6), dim3(256), 0, stream>>>(xn, Wq, Wk, Wv,
                                                    bihq, bhhq, bihk, bhhk, bihv, bhhv, gxb);
    k_lstm<<<dim3(768), dim3(256), 0, stream>>>(gxb, Whq, Whk, Whv, qkv);
    k_attn<<<dim3(1024), dim3(256), 0, stream>>>(qkv, wvb);
    k_post<<<dim3(8, 256, 4), dim3(256), 0, stream>>>(wvb, in, g2, b2,
                                                      Wr, br, Wi, bi, g3, b3, pa, outp);
}

// Round 2
// 772.897 us; speedup vs baseline: 1.3497x; 1.3497x over previous
//
#include <hip/hip_runtime.h>
#include <hip/hip_bf16.h>
#include <stddef.h>

// Sizes: N=4, C=64, F=256, T=256, B=N*F=1024, D=128, H=32, 4H=128, NG=384

typedef __bf16 bf16x8 __attribute__((ext_vector_type(8)));
typedef float f32x4 __attribute__((ext_vector_type(4)));

__device__ __forceinline__ ushort f2bf(float x) {   // RTNE
    uint u = __builtin_bit_cast(uint, x);
    uint r = (u + 0x7fffu + ((u >> 16) & 1u)) >> 16;
    return (ushort)r;
}
__device__ __forceinline__ float bflo2f(uint v) {   // low 16 bits -> float
    return __builtin_bit_cast(float, v << 16);
}
__device__ __forceinline__ float bfhi2f(uint v) {   // high 16 bits -> float
    return __builtin_bit_cast(float, v & 0xffff0000u);
}

__device__ __forceinline__ float fsig(float x) {
    return __builtin_amdgcn_rcpf(1.f + __expf(-x));
}
__device__ __forceinline__ float ftanh(float x) {
    return 1.f - 2.f * __builtin_amdgcn_rcpf(__expf(2.f * x) + 1.f);
}
__device__ __forceinline__ float wredsum(float v) {
#pragma unroll
    for (int off = 32; off; off >>= 1) v += __shfl_xor(v, off);
    return v;
}
__device__ __forceinline__ float wredmax(float v) {
#pragma unroll
    for (int off = 32; off; off >>= 1) v = fmaxf(v, __shfl_xor(v, off));
    return v;
}
__device__ __forceinline__ float hredsum(float v) {
#pragma unroll
    for (int off = 16; off; off >>= 1) v += __shfl_xor(v, off);
    return v;
}

// ---------------------------------------------------------------------------
// Kernel 1: inputs [N,C,F,T,2] -> xn [B,T,128] (bf16) with LN1 fused.
// ---------------------------------------------------------------------------
__global__ __launch_bounds__(256) void k_prep(const float* __restrict__ in,
                                              const float* __restrict__ g1,
                                              const float* __restrict__ b1,
                                              ushort* __restrict__ xn) {
    __shared__ float xl[32][129];
    const int n = blockIdx.z, f = blockIdx.y, t0 = blockIdx.x * 32;
    const int tid = threadIdx.x;
    const int c = tid >> 2, q = tid & 3;
    const float* src = in + ((size_t)(n * 64 + c) * 256 + f) * 512 + t0 * 2 + q * 16;
#pragma unroll
    for (int e = 0; e < 4; ++e) {
        float4 v4 = *(const float4*)(src + e * 4);
        int dt = q * 8 + e * 2;
        xl[dt][c]          = v4.x;
        xl[dt][c + 64]     = v4.y;
        xl[dt + 1][c]      = v4.z;
        xl[dt + 1][c + 64] = v4.w;
    }
    __syncthreads();
    const int lane = tid & 63, w = tid >> 6;
    const int b = n * 256 + f;
#pragma unroll 1
    for (int r = 0; r < 8; ++r) {
        int dt = w * 8 + r;
        float a = xl[dt][lane], bb = xl[dt][lane + 64];
        float s = wredsum(a + bb);
        float mean = s * 0.0078125f;
        float da = a - mean, db = bb - mean;
        float var = wredsum(da * da + db * db) * 0.0078125f;
        float inv = __builtin_amdgcn_rsqf(var + 1e-5f);
        size_t base = ((size_t)b * 256 + (t0 + dt)) * 128;
        xn[base + lane]      = f2bf(da * inv * g1[lane] + b1[lane]);
        xn[base + lane + 64] = f2bf(db * inv * g1[lane + 64] + b1[lane + 64]);
    }
}

// ---------------------------------------------------------------------------
// Kernel 2 (MFMA): gx[M,384](bf16) = xn[M,128](bf16) @ Wcat^T + (bih+bhh)
// block: BM=128 x BN=64, K=128 single stage. 4 waves, each 64x32 output.
// ---------------------------------------------------------------------------
__global__ __launch_bounds__(256) void k_gemm(const ushort* __restrict__ xn,
                                              const float* __restrict__ Wq,
                                              const float* __restrict__ Wk,
                                              const float* __restrict__ Wv,
                                              const float* __restrict__ bihq, const float* __restrict__ bhhq,
                                              const float* __restrict__ bihk, const float* __restrict__ bhhk,
                                              const float* __restrict__ bihv, const float* __restrict__ bhhv,
                                              ushort* __restrict__ gx) {
    __shared__ ushort a_lds[128 * 136];   // row stride 136 ushorts = 272B (16B-mult, odd-ish)
    __shared__ ushort w_lds[64 * 136];
    const int tid = threadIdx.x;
    const int m0 = blockIdx.x * 128;
    const int yb = blockIdx.y;
    const int l = yb >> 1, n0 = (yb & 1) * 64;
    const float* W   = (l == 0) ? Wq   : (l == 1) ? Wk   : Wv;
    const float* bih = (l == 0) ? bihq : (l == 1) ? bihk : bihv;
    const float* bhh = (l == 0) ? bhhq : (l == 1) ? bhhk : bhhv;

    // stage A: 128 rows x 128 bf16 (16 chunks of 8 bf16 per row)
#pragma unroll
    for (int p = 0; p < 8; ++p) {
        int idx = p * 256 + tid;
        int r = idx >> 4, c = idx & 15;
        uint4 v = *(const uint4*)(xn + (size_t)(m0 + r) * 128 + c * 8);
        *(uint4*)&a_lds[r * 136 + c * 8] = v;
    }
    // stage W: 64 rows x 128 fp32 -> bf16
#pragma unroll
    for (int p = 0; p < 4; ++p) {
        int idx = p * 256 + tid;
        int r = idx >> 4, c = idx & 15;
        const float* wp = W + (size_t)(n0 + r) * 128 + c * 8;
        float4 wa = *(const float4*)wp;
        float4 wb = *(const float4*)(wp + 4);
        union { ushort u[8]; uint4 v; } pk;
        pk.u[0] = f2bf(wa.x); pk.u[1] = f2bf(wa.y); pk.u[2] = f2bf(wa.z); pk.u[3] = f2bf(wa.w);
        pk.u[4] = f2bf(wb.x); pk.u[5] = f2bf(wb.y); pk.u[6] = f2bf(wb.z); pk.u[7] = f2bf(wb.w);
        *(uint4*)&w_lds[r * 136 + c * 8] = pk.v;
    }
    __syncthreads();

    const int w = tid >> 6, lane = tid & 63;
    const int wr = w >> 1, wc = w & 1;
    const int row16 = lane & 15, koct = lane >> 4;

    f32x4 acc[4][2];
#pragma unroll
    for (int mi = 0; mi < 4; ++mi)
#pragma unroll
        for (int ni = 0; ni < 2; ++ni) acc[mi][ni] = (f32x4){0.f, 0.f, 0.f, 0.f};

#pragma unroll
    for (int ki = 0; ki < 4; ++ki) {
        bf16x8 af[4], bfr[2];
#pragma unroll
        for (int mi = 0; mi < 4; ++mi)
            af[mi] = *(const bf16x8*)&a_lds[(wr * 64 + mi * 16 + row16) * 136 + ki * 32 + koct * 8];
#pragma unroll
        for (int ni = 0; ni < 2; ++ni)
            bfr[ni] = *(const bf16x8*)&w_lds[(wc * 32 + ni * 16 + row16) * 136 + ki * 32 + koct * 8];
#pragma unroll
        for (int mi = 0; mi < 4; ++mi)
#pragma unroll
            for (int ni = 0; ni < 2; ++ni)
                acc[mi][ni] = __builtin_amdgcn_mfma_f32_16x16x32_bf16(af[mi], bfr[ni], acc[mi][ni], 0, 0, 0);
    }

    // epilogue: + bias, cvt bf16, store. D: col=lane&15, row=(lane>>4)*4+q
    float bs[2];
#pragma unroll
    for (int ni = 0; ni < 2; ++ni) {
        int ncol = n0 + wc * 32 + ni * 16 + row16;
        bs[ni] = bih[ncol] + bhh[ncol];
    }
#pragma unroll
    for (int mi = 0; mi < 4; ++mi)
#pragma unroll
        for (int ni = 0; ni < 2; ++ni) {
            int ncol = n0 + wc * 32 + ni * 16 + row16;
#pragma unroll
            for (int q = 0; q < 4; ++q) {
                size_t m = (size_t)m0 + wr * 64 + mi * 16 + koct * 4 + q;
                gx[m * 384 + l * 128 + ncol] = f2bf(acc[mi][ni][q] + bs[ni]);
            }
        }
}

// ---------------------------------------------------------------------------
// Kernel 3: LSTM recurrence. One wave per (l, b). gx is bf16 now.
// ---------------------------------------------------------------------------
__global__ __launch_bounds__(256) void k_lstm(const ushort* __restrict__ gx,
                                              const float* __restrict__ Whq,
                                              const float* __restrict__ Whk,
                                              const float* __restrict__ Whv,
                                              float* __restrict__ qkv) {
    __shared__ float hbuf[4][32];
    __shared__ float gbuf[4][128];
    const int tid = threadIdx.x, w = tid >> 6, lane = tid & 63;
    const int sid = blockIdx.x * 4 + w;
    const int l = sid >> 10, b = sid & 1023;
    const float* Wh = (l == 0) ? Whq : (l == 1) ? Whk : Whv;
    float w0[32], w1[32];
    {
        const float4* r0 = (const float4*)(Wh + (size_t)(2 * lane) * 32);
        const float4* r1 = (const float4*)(Wh + (size_t)(2 * lane + 1) * 32);
#pragma unroll
        for (int e = 0; e < 8; ++e) {
            float4 a = r0[e];
            w0[4 * e] = a.x; w0[4 * e + 1] = a.y; w0[4 * e + 2] = a.z; w0[4 * e + 3] = a.w;
            float4 c4 = r1[e];
            w1[4 * e] = c4.x; w1[4 * e + 1] = c4.y; w1[4 * e + 2] = c4.z; w1[4 * e + 3] = c4.w;
        }
    }
    if (lane < 32) hbuf[w][lane] = 0.f;
    float c = 0.f;
    const ushort* gp = gx + (size_t)b * 98304 + l * 128 + 2 * lane;  // 98304 = 256*384
    float* outp = qkv + (size_t)sid * 8192;
    uint gc  = *(const uint*)gp;
    uint g1v = *(const uint*)(gp + 384);
    for (int t = 0; t < 256; ++t) {
        uint g2v = 0;
        if (t + 2 < 256) g2v = *(const uint*)(gp + (size_t)(t + 2) * 384);
        float p0 = 0.f, p1 = 0.f, q0 = 0.f, q1 = 0.f;
#pragma unroll
        for (int jj = 0; jj < 8; ++jj) {
            float4 h4 = *(const float4*)&hbuf[w][jj * 4];
            if (jj & 1) {
                p1 += w0[4 * jj] * h4.x; p1 += w0[4 * jj + 1] * h4.y;
                p1 += w0[4 * jj + 2] * h4.z; p1 += w0[4 * jj + 3] * h4.w;
                q1 += w1[4 * jj] * h4.x; q1 += w1[4 * jj + 1] * h4.y;
                q1 += w1[4 * jj + 2] * h4.z; q1 += w1[4 * jj + 3] * h4.w;
            } else {
                p0 += w0[4 * jj] * h4.x; p0 += w0[4 * jj + 1] * h4.y;
                p0 += w0[4 * jj + 2] * h4.z; p0 += w0[4 * jj + 3] * h4.w;
                q0 += w1[4 * jj] * h4.x; q0 += w1[4 * jj + 1] * h4.y;
                q0 += w1[4 * jj + 2] * h4.z; q0 += w1[4 * jj + 3] * h4.w;
            }
        }
        float g0 = bflo2f(gc) + p0 + p1;
        float g1 = bfhi2f(gc) + q0 + q1;
        *(float2*)&gbuf[w][2 * lane] = make_float2(g0, g1);
        if (lane < 32) {
            float gi = gbuf[w][lane];
            float gf = gbuf[w][lane + 32];
            float gg = gbuf[w][lane + 64];
            float go = gbuf[w][lane + 96];
            c = fsig(gf) * c + fsig(gi) * ftanh(gg);
            float hN = fsig(go) * ftanh(c);
            hbuf[w][lane] = hN;
            outp[(size_t)t * 32 + lane] = hN;
        }
        gc = g1v; g1v = g2v;
    }
}

// ---------------------------------------------------------------------------
// Kernel 4: attention (unchanged)
// ---------------------------------------------------------------------------
__global__ __launch_bounds__(256) void k_attn(const float* __restrict__ qkv,
                                              float* __restrict__ wvout) {
    __shared__ float k_lds[256][33];
    __shared__ float attn_s[4][2][256];
    const int tid = threadIdx.x, w = tid >> 6, lane = tid & 63;
    const int b = blockIdx.x;
    const float* qb = qkv;
    const float* kb = qkv + 8388608;
    const float* vb = qkv + 16777216;
    for (int idx = tid; idx < 8192; idx += 256) {
        int s = idx >> 5, j = idx & 31;
        k_lds[s][j] = kb[(size_t)b * 8192 + idx];
    }
    __syncthreads();
    const int jj = lane & 31, half = lane >> 5;
    const float* vrow = vb + (size_t)b * 8192;
    for (int i = 0; i < 32; ++i) {
        const int tA = w + i * 4;
        const int tB = tA + 128;
        float qa[32], qc[32];
        const float4* qAp = (const float4*)(qb + ((size_t)b * 256 + tA) * 32);
        const float4* qBp = (const float4*)(qb + ((size_t)b * 256 + tB) * 32);
#pragma unroll
        for (int e = 0; e < 8; ++e) {
            float4 x4 = qAp[e];
            qa[4 * e] = x4.x; qa[4 * e + 1] = x4.y; qa[4 * e + 2] = x4.z; qa[4 * e + 3] = x4.w;
            float4 y4 = qBp[e];
            qc[4 * e] = y4.x; qc[4 * e + 1] = y4.y; qc[4 * e + 2] = y4.z; qc[4 * e + 3] = y4.w;
        }
        float eA[4] = {0, 0, 0, 0}, eB[4] = {0, 0, 0, 0};
#pragma unroll
        for (int j = 0; j < 32; ++j) {
            float qaj = qa[j], qcj = qc[j];
#pragma unroll
            for (int m = 0; m < 4; ++m) {
                float kv = k_lds[lane + (m << 6)][j];
                eA[m] += qaj * kv;
                eB[m] += qcj * kv;
            }
        }
        float mA = -1e30f, mB = -1e30f;
#pragma unroll
        for (int m = 0; m < 4; ++m) {
            int s = lane + (m << 6);
            eA[m] = (s <= tA) ? eA[m] * 0.25f : 0.f;
            eB[m] = (s <= tB) ? eB[m] * 0.25f : 0.f;
            mA = fmaxf(mA, eA[m]); mB = fmaxf(mB, eB[m]);
        }
        mA = wredmax(mA); mB = wredmax(mB);
        float sA = 0.f, sB = 0.f, pA[4], pB[4];
#pragma unroll
        for (int m = 0; m < 4; ++m) {
            pA[m] = __expf(eA[m] - mA); sA += pA[m];
            pB[m] = __expf(eB[m] - mB); sB += pB[m];
        }
        sA = wredsum(sA); sB = wredsum(sB);
        float rA = __builtin_amdgcn_rcpf(sA), rB = __builtin_amdgcn_rcpf(sB);
#pragma unroll
        for (int m = 0; m < 4; ++m) {
            attn_s[w][0][lane + (m << 6)] = pA[m] * rA;
            attn_s[w][1][lane + (m << 6)] = pB[m] * rB;
        }
        float aAx = 0, aAy = 0, aAz = 0, aAw = 0;
        float aBx = 0, aBy = 0, aBz = 0, aBw = 0;
#pragma unroll 4
        for (int s4 = 0; s4 < 32; ++s4) {
            int s0 = (half << 7) + (s4 << 2);
            float4 a4 = *(const float4*)&attn_s[w][0][s0];
            float4 c4 = *(const float4*)&attn_s[w][1][s0];
            float v0 = vrow[(size_t)s0 * 32 + jj];
            float v1 = vrow[(size_t)(s0 + 1) * 32 + jj];
            float v2 = vrow[(size_t)(s0 + 2) * 32 + jj];
            float v3 = vrow[(size_t)(s0 + 3) * 32 + jj];
            aAx += a4.x * v0; aAy += a4.y * v1; aAz += a4.z * v2; aAw += a4.w * v3;
            aBx += c4.x * v0; aBy += c4.y * v1; aBz += c4.z * v2; aBw += c4.w * v3;
        }
        float accA = (aAx + aAy) + (aAz + aAw);
        float accB = (aBx + aBy) + (aBz + aBw);
        accA += __shfl_down(accA, 32);
        accB += __shfl_down(accB, 32);
        if (lane < 32) {
            wvout[((size_t)b * 256 + tA) * 32 + lane] = accA;
            wvout[((size_t)b * 256 + tB) * 32 + lane] = accB;
        }
    }
}

// ---------------------------------------------------------------------------
// Kernel 5: LN2 + complex linear + LN3 + PReLU + residual (unchanged)
// ---------------------------------------------------------------------------
__global__ __launch_bounds__(256) void k_post(const float* __restrict__ wv,
                                              const float* __restrict__ in,
                                              const float* __restrict__ g2,
                                              const float* __restrict__ b2,
                                              const float* __restrict__ Wr,
                                              const float* __restrict__ br,
                                              const float* __restrict__ Wi,
                                              const float* __restrict__ bi,
                                              const float* __restrict__ g3,
                                              const float* __restrict__ b3,
                                              const float* __restrict__ pa,
                                              float* __restrict__ outp) {
    __shared__ float xv[32][33];
    __shared__ float wr_l[64][17], wi_l[64][17];
    __shared__ float out_s[64][65];
    const int tid = threadIdx.x;
    const int n = blockIdx.z, f = blockIdx.y, t0 = blockIdx.x * 32;
    const int b = n * 256 + f;
    for (int idx = tid; idx < 1024; idx += 256) {
        int dt = idx >> 5, j = idx & 31;
        xv[dt][j] = wv[((size_t)b * 256 + t0 + dt) * 32 + j];
        int cc = idx >> 4, jjj = idx & 15;
        wr_l[cc][jjj] = Wr[idx];
        wi_l[cc][jjj] = Wi[idx];
    }
    __syncthreads();
    const int lane = tid & 63, w = tid >> 6;
#pragma unroll 1
    for (int r = 0; r < 4; ++r) {
        int dt = w * 8 + r * 2 + (lane >> 5);
        int j = lane & 31;
        float v = xv[dt][j];
        float mean = hredsum(v) * 0.03125f;
        float d = v - mean;
        float var = hredsum(d * d) * 0.03125f;
        float inv = __builtin_amdgcn_rsqf(var + 1e-5f);
        xv[dt][j] = d * inv * g2[j] + b2[j];
    }
    __syncthreads();
    const int c = lane;
    const float g3c = g3[c], b3c = b3[c];
    const float bd = br[c] - bi[c], bsum = br[c] + bi[c];
    const float alpha = pa[0];
#pragma unroll 1
    for (int r = 0; r < 8; ++r) {
        int dt = w * 8 + r;
        float re = 0.f, im = 0.f;
#pragma unroll
        for (int j = 0; j < 16; ++j) {
            float xr = xv[dt][j], xi2 = xv[dt][16 + j];
            float wrv = wr_l[c][j], wiv = wi_l[c][j];
            re += xr * wrv; re -= xi2 * wiv;
            im += xi2 * wrv; im += xr * wiv;
        }
        re += bd; im += bsum;
        float mR = wredsum(re) * 0.015625f;
        float dR = re - mR;
        float vR = wredsum(dR * dR) * 0.015625f;
        float nR = dR * __builtin_amdgcn_rsqf(vR + 1e-5f) * g3c + b3c;
        nR = (nR >= 0.f) ? nR : alpha * nR;
        float mI = wredsum(im) * 0.015625f;
        float dI = im - mI;
        float vI = wredsum(dI * dI) * 0.015625f;
        float nI = dI * __builtin_amdgcn_rsqf(vI + 1e-5f) * g3c + b3c;
        nI = (nI >= 0.f) ? nI : alpha * nI;
        out_s[c][dt * 2]     = nR;
        out_s[c][dt * 2 + 1] = nI;
    }
    __syncthreads();
    const int cc = tid >> 2, q = tid & 3;
    size_t base = ((size_t)(n * 64 + cc) * 256 + f) * 512 + t0 * 2 + q * 16;
#pragma unroll
    for (int e = 0; e < 4; ++e) {
        float4 iv = *(const float4*)(in + base + e * 4);
        int k0 = q * 16 + e * 4;
        float4 ov;
        ov.x = out_s[cc][k0]     + iv.x;
        ov.y = out_s[cc][k0 + 1] + iv.y;
        ov.z = out_s[cc][k0 + 2] + iv.z;
        ov.w = out_s[cc][k0 + 3] + iv.w;
        *(float4*)(outp + base + e * 4) = ov;
    }
}

// ---------------------------------------------------------------------------
extern "C" void kernel_launch(void* const* d_in, const int* in_sizes, int n_in,
                              void* d_out, int out_size, void* d_ws, size_t ws_size,
                              hipStream_t stream) {
    const float* in   = (const float*)d_in[0];
    const float* g1   = (const float*)d_in[1];
    const float* b1   = (const float*)d_in[2];
    const float* Wq   = (const float*)d_in[3];
    const float* Whq  = (const float*)d_in[4];
    const float* bihq = (const float*)d_in[5];
    const float* bhhq = (const float*)d_in[6];
    const float* Wk   = (const float*)d_in[7];
    const float* Whk  = (const float*)d_in[8];
    const float* bihk = (const float*)d_in[9];
    const float* bhhk = (const float*)d_in[10];
    const float* Wv   = (const float*)d_in[11];
    const float* Whv  = (const float*)d_in[12];
    const float* bihv = (const float*)d_in[13];
    const float* bhhv = (const float*)d_in[14];
    const float* g2   = (const float*)d_in[15];
    const float* b2   = (const float*)d_in[16];
    const float* Wr   = (const float*)d_in[17];
    const float* br   = (const float*)d_in[18];
    const float* Wi   = (const float*)d_in[19];
    const float* bi   = (const float*)d_in[20];
    const float* g3   = (const float*)d_in[21];
    const float* b3   = (const float*)d_in[22];
    const float* pa   = (const float*)d_in[23];
    float* outp = (float*)d_out;

    // workspace layout (bytes):
    // [0, 201326592)            gx bf16  262144*384*2
    // [201326592, 268435456)    xn bf16  262144*128*2
    // [268435456, 369098752)    qkv fp32 3*262144*32*4
    // [369098752, 402653184)    wv  fp32
    ushort* gxb = (ushort*)d_ws;
    ushort* xnb = (ushort*)((char*)d_ws + 201326592);
    float*  qkv = (float*)((char*)d_ws + 268435456);
    float*  wvb = (float*)((char*)d_ws + 369098752);

    k_prep<<<dim3(8, 256, 4), dim3(256), 0, stream>>>(in, g1, b1, xnb);
    k_gemm<<<dim3(2048, 6), dim3(256), 0, stream>>>(xnb, Wq, Wk, Wv,
                                                    bihq, bhhq, bihk, bhhk, bihv, bhhv, gxb);
    k_lstm<<<dim3(768), dim3(256), 0, stream>>>(gxb, Whq, Whk, Whv, qkv);
    k_attn<<<dim3(1024), dim3(256), 0, stream>>>(qkv, wvb);
    k_post<<<dim3(8, 256, 4), dim3(256), 0, stream>>>(wvb, in, g2, b2,
                                                      Wr, br, Wi, bi, g3, b3, pa, outp);
}

// Round 4
// 547.858 us; speedup vs baseline: 1.9041x; 1.4108x over previous
//
#include <hip/hip_runtime.h>
#include <hip/hip_bf16.h>
#include <stddef.h>

// Sizes: N=4, C=64, F=256, T=256, B=N*F=1024, D=128, H=32, 4H=128, NG=384

typedef __bf16 bf16x8 __attribute__((ext_vector_type(8)));
typedef float f32x4 __attribute__((ext_vector_type(4)));

__device__ __forceinline__ ushort f2bf(float x) {   // RTNE
    uint u = __builtin_bit_cast(uint, x);
    uint r = (u + 0x7fffu + ((u >> 16) & 1u)) >> 16;
    return (ushort)r;
}
__device__ __forceinline__ float bflo2f(uint v) {
    return __builtin_bit_cast(float, v << 16);
}
__device__ __forceinline__ float bfhi2f(uint v) {
    return __builtin_bit_cast(float, v & 0xffff0000u);
}

__device__ __forceinline__ float fsig(float x) {
    return __builtin_amdgcn_rcpf(1.f + __expf(-x));
}
__device__ __forceinline__ float ftanh(float x) {
    return 1.f - 2.f * __builtin_amdgcn_rcpf(__expf(2.f * x) + 1.f);
}
__device__ __forceinline__ float wredsum(float v) {
#pragma unroll
    for (int off = 32; off; off >>= 1) v += __shfl_xor(v, off);
    return v;
}
__device__ __forceinline__ float hredsum(float v) {
#pragma unroll
    for (int off = 16; off; off >>= 1) v += __shfl_xor(v, off);
    return v;
}

// ---------------------------------------------------------------------------
// Kernel 1: inputs [N,C,F,T,2] -> xn [B,T,128] (bf16) with LN1 fused.
// ---------------------------------------------------------------------------
__global__ __launch_bounds__(256) void k_prep(const float* __restrict__ in,
                                              const float* __restrict__ g1,
                                              const float* __restrict__ b1,
                                              ushort* __restrict__ xn) {
    __shared__ float xl[32][129];
    const int n = blockIdx.z, f = blockIdx.y, t0 = blockIdx.x * 32;
    const int tid = threadIdx.x;
    const int c = tid >> 2, q = tid & 3;
    const float* src = in + ((size_t)(n * 64 + c) * 256 + f) * 512 + t0 * 2 + q * 16;
#pragma unroll
    for (int e = 0; e < 4; ++e) {
        float4 v4 = *(const float4*)(src + e * 4);
        int dt = q * 8 + e * 2;
        xl[dt][c]          = v4.x;
        xl[dt][c + 64]     = v4.y;
        xl[dt + 1][c]      = v4.z;
        xl[dt + 1][c + 64] = v4.w;
    }
    __syncthreads();
    const int lane = tid & 63, w = tid >> 6;
    const int b = n * 256 + f;
#pragma unroll 1
    for (int r = 0; r < 8; ++r) {
        int dt = w * 8 + r;
        float a = xl[dt][lane], bb = xl[dt][lane + 64];
        float s = wredsum(a + bb);
        float mean = s * 0.0078125f;
        float da = a - mean, db = bb - mean;
        float var = wredsum(da * da + db * db) * 0.0078125f;
        float inv = __builtin_amdgcn_rsqf(var + 1e-5f);
        size_t base = ((size_t)b * 256 + (t0 + dt)) * 128;
        xn[base + lane]      = f2bf(da * inv * g1[lane] + b1[lane]);
        xn[base + lane + 64] = f2bf(db * inv * g1[lane + 64] + b1[lane + 64]);
    }
}

// ---------------------------------------------------------------------------
// Kernel 2 (MFMA): gx[M,384](bf16) = xn[M,128](bf16) @ Wcat^T + (bih+bhh)
// ---------------------------------------------------------------------------
__global__ __launch_bounds__(256) void k_gemm(const ushort* __restrict__ xn,
                                              const float* __restrict__ Wq,
                                              const float* __restrict__ Wk,
                                              const float* __restrict__ Wv,
                                              const float* __restrict__ bihq, const float* __restrict__ bhhq,
                                              const float* __restrict__ bihk, const float* __restrict__ bhhk,
                                              const float* __restrict__ bihv, const float* __restrict__ bhhv,
                                              ushort* __restrict__ gx) {
    __shared__ ushort a_lds[128 * 136];
    __shared__ ushort w_lds[64 * 136];
    const int tid = threadIdx.x;
    const int m0 = blockIdx.x * 128;
    const int yb = blockIdx.y;
    const int l = yb >> 1, n0 = (yb & 1) * 64;
    const float* W   = (l == 0) ? Wq   : (l == 1) ? Wk   : Wv;
    const float* bih = (l == 0) ? bihq : (l == 1) ? bihk : bihv;
    const float* bhh = (l == 0) ? bhhq : (l == 1) ? bhhk : bhhv;

#pragma unroll
    for (int p = 0; p < 8; ++p) {
        int idx = p * 256 + tid;
        int r = idx >> 4, c = idx & 15;
        uint4 v = *(const uint4*)(xn + (size_t)(m0 + r) * 128 + c * 8);
        *(uint4*)&a_lds[r * 136 + c * 8] = v;
    }
#pragma unroll
    for (int p = 0; p < 4; ++p) {
        int idx = p * 256 + tid;
        int r = idx >> 4, c = idx & 15;
        const float* wp = W + (size_t)(n0 + r) * 128 + c * 8;
        float4 wa = *(const float4*)wp;
        float4 wb = *(const float4*)(wp + 4);
        union { ushort u[8]; uint4 v; } pk;
        pk.u[0] = f2bf(wa.x); pk.u[1] = f2bf(wa.y); pk.u[2] = f2bf(wa.z); pk.u[3] = f2bf(wa.w);
        pk.u[4] = f2bf(wb.x); pk.u[5] = f2bf(wb.y); pk.u[6] = f2bf(wb.z); pk.u[7] = f2bf(wb.w);
        *(uint4*)&w_lds[r * 136 + c * 8] = pk.v;
    }
    __syncthreads();

    const int w = tid >> 6, lane = tid & 63;
    const int wr = w >> 1, wc = w & 1;
    const int row16 = lane & 15, koct = lane >> 4;

    f32x4 acc[4][2];
#pragma unroll
    for (int mi = 0; mi < 4; ++mi)
#pragma unroll
        for (int ni = 0; ni < 2; ++ni) acc[mi][ni] = (f32x4){0.f, 0.f, 0.f, 0.f};

#pragma unroll
    for (int ki = 0; ki < 4; ++ki) {
        bf16x8 af[4], bfr[2];
#pragma unroll
        for (int mi = 0; mi < 4; ++mi)
            af[mi] = *(const bf16x8*)&a_lds[(wr * 64 + mi * 16 + row16) * 136 + ki * 32 + koct * 8];
#pragma unroll
        for (int ni = 0; ni < 2; ++ni)
            bfr[ni] = *(const bf16x8*)&w_lds[(wc * 32 + ni * 16 + row16) * 136 + ki * 32 + koct * 8];
#pragma unroll
        for (int mi = 0; mi < 4; ++mi)
#pragma unroll
            for (int ni = 0; ni < 2; ++ni)
                acc[mi][ni] = __builtin_amdgcn_mfma_f32_16x16x32_bf16(af[mi], bfr[ni], acc[mi][ni], 0, 0, 0);
    }

    float bs[2];
#pragma unroll
    for (int ni = 0; ni < 2; ++ni) {
        int ncol = n0 + wc * 32 + ni * 16 + row16;
        bs[ni] = bih[ncol] + bhh[ncol];
    }
#pragma unroll
    for (int mi = 0; mi < 4; ++mi)
#pragma unroll
        for (int ni = 0; ni < 2; ++ni) {
            int ncol = n0 + wc * 32 + ni * 16 + row16;
#pragma unroll
            for (int q = 0; q < 4; ++q) {
                size_t m = (size_t)m0 + wr * 64 + mi * 16 + koct * 4 + q;
                gx[m * 384 + l * 128 + ncol] = f2bf(acc[mi][ni][q] + bs[ni]);
            }
        }
}

// ---------------------------------------------------------------------------
// Kernel 3: LSTM recurrence. One wave per (l, b). Writes q/k/v as bf16.
// ---------------------------------------------------------------------------
__global__ __launch_bounds__(256) void k_lstm(const ushort* __restrict__ gx,
                                              const float* __restrict__ Whq,
                                              const float* __restrict__ Whk,
                                              const float* __restrict__ Whv,
                                              ushort* __restrict__ qkv) {
    __shared__ float hbuf[4][32];
    __shared__ float gbuf[4][128];
    const int tid = threadIdx.x, w = tid >> 6, lane = tid & 63;
    const int sid = blockIdx.x * 4 + w;
    const int l = sid >> 10, b = sid & 1023;
    const float* Wh = (l == 0) ? Whq : (l == 1) ? Whk : Whv;
    float w0[32], w1[32];
    {
        const float4* r0 = (const float4*)(Wh + (size_t)(2 * lane) * 32);
        const float4* r1 = (const float4*)(Wh + (size_t)(2 * lane + 1) * 32);
#pragma unroll
        for (int e = 0; e < 8; ++e) {
            float4 a = r0[e];
            w0[4 * e] = a.x; w0[4 * e + 1] = a.y; w0[4 * e + 2] = a.z; w0[4 * e + 3] = a.w;
            float4 c4 = r1[e];
            w1[4 * e] = c4.x; w1[4 * e + 1] = c4.y; w1[4 * e + 2] = c4.z; w1[4 * e + 3] = c4.w;
        }
    }
    if (lane < 32) hbuf[w][lane] = 0.f;
    float c = 0.f;
    const ushort* gp = gx + (size_t)b * 98304 + l * 128 + 2 * lane;
    ushort* outp = qkv + (size_t)sid * 8192;
    uint gc  = *(const uint*)gp;
    uint g1v = *(const uint*)(gp + 384);
    for (int t = 0; t < 256; ++t) {
        uint g2v = 0;
        if (t + 2 < 256) g2v = *(const uint*)(gp + (size_t)(t + 2) * 384);
        float p0 = 0.f, p1 = 0.f, q0 = 0.f, q1 = 0.f;
#pragma unroll
        for (int jj = 0; jj < 8; ++jj) {
            float4 h4 = *(const float4*)&hbuf[w][jj * 4];
            if (jj & 1) {
                p1 += w0[4 * jj] * h4.x; p1 += w0[4 * jj + 1] * h4.y;
                p1 += w0[4 * jj + 2] * h4.z; p1 += w0[4 * jj + 3] * h4.w;
                q1 += w1[4 * jj] * h4.x; q1 += w1[4 * jj + 1] * h4.y;
                q1 += w1[4 * jj + 2] * h4.z; q1 += w1[4 * jj + 3] * h4.w;
            } else {
                p0 += w0[4 * jj] * h4.x; p0 += w0[4 * jj + 1] * h4.y;
                p0 += w0[4 * jj + 2] * h4.z; p0 += w0[4 * jj + 3] * h4.w;
                q0 += w1[4 * jj] * h4.x; q0 += w1[4 * jj + 1] * h4.y;
                q0 += w1[4 * jj + 2] * h4.z; q0 += w1[4 * jj + 3] * h4.w;
            }
        }
        float g0 = bflo2f(gc) + p0 + p1;
        float g1 = bfhi2f(gc) + q0 + q1;
        *(float2*)&gbuf[w][2 * lane] = make_float2(g0, g1);
        if (lane < 32) {
            float gi = gbuf[w][lane];
            float gf = gbuf[w][lane + 32];
            float gg = gbuf[w][lane + 64];
            float go = gbuf[w][lane + 96];
            c = fsig(gf) * c + fsig(gi) * ftanh(gg);
            float hN = fsig(go) * ftanh(c);
            hbuf[w][lane] = hN;
            outp[(size_t)t * 32 + lane] = f2bf(hN);
        }
        gc = g1v; g1v = g2v;
    }
}

// ---------------------------------------------------------------------------
// Kernel 4 (MFMA): attention. 1 block per b, 4 waves x 64 q-rows each.
// K[256][32] LDS chunk-XOR swizzled; V^T[32][256] swizzled; P per-wave LDS.
// Multiplicative tril mask: masked energies = exact 0, included in softmax.
// ---------------------------------------------------------------------------
__global__ __launch_bounds__(256) void k_attn(const ushort* __restrict__ qkvb,
                                              float* __restrict__ wvout) {
    __shared__ ushort k_sw[256 * 32];      // 16 KiB
    __shared__ ushort vt_sw[32 * 256];     // 16 KiB
    __shared__ ushort p_sw[4][16 * 256];   // 32 KiB (per-wave private)
    const int tid = threadIdx.x, w = tid >> 6, lane = tid & 63;
    const int b = blockIdx.x;
    const ushort* qb = qkvb + (size_t)b * 8192;
    const ushort* kb = qkvb + 8388608 + (size_t)b * 8192;
    const ushort* vb = qkvb + 16777216 + (size_t)b * 8192;
    // stage K (swizzled row-major) and V^T (swizzled): 1024 chunks of 8 bf16 each
#pragma unroll
    for (int p = 0; p < 4; ++p) {
        int idx = p * 256 + tid;           // 0..1023 chunks of 8 bf16
        int s = idx >> 2, cc = idx & 3;
        uint4 kv = *(const uint4*)(kb + s * 32 + cc * 8);
        int cK = cc ^ ((s >> 1) & 3);
        *(uint4*)&k_sw[s * 32 + cK * 8] = kv;
        uint4 vv = *(const uint4*)(vb + s * 32 + cc * 8);
        union { uint4 v; ushort u[8]; } un; un.v = vv;
#pragma unroll
        for (int e = 0; e < 8; ++e) {
            int row = cc * 8 + e;
            vt_sw[row * 256 + (((s >> 3) ^ (row & 7)) << 3) + (s & 7)] = un.u[e];
        }
    }
    __syncthreads();
    const int r16 = lane & 15, koct = lane >> 4;
    ushort* pw = p_sw[w];
    // Q fragments for this wave's 4 t-blocks (row = lane&15, k = koct*8..+7)
    bf16x8 qf[4];
#pragma unroll
    for (int i = 0; i < 4; ++i) {
        int t = (w * 4 + i) * 16 + r16;
        qf[i] = *(const bf16x8*)(qb + t * 32 + koct * 8);
    }
#pragma unroll 1
    for (int i = 0; i < 4; ++i) {
        const int tb = (w * 4 + i) * 16;
        f32x4 acc[16];
#pragma unroll
        for (int st = 0; st < 16; ++st) acc[st] = (f32x4){0.f, 0.f, 0.f, 0.f};
        // S = Q K^T : 16 s-tiles, one MFMA each (K dim = 32)
#pragma unroll
        for (int st = 0; st < 16; ++st) {
            int s = st * 16 + r16;
            int cK = koct ^ ((s >> 1) & 3);
            bf16x8 kf = *(const bf16x8*)&k_sw[s * 32 + cK * 8];
            acc[st] = __builtin_amdgcn_mfma_f32_16x16x32_bf16(qf[i], kf, acc[st], 0, 0, 0);
        }
        // multiplicative mask + scale; row max (includes zeros)
        float mx[4] = {-1e30f, -1e30f, -1e30f, -1e30f};
#pragma unroll
        for (int st = 0; st < 16; ++st) {
            int s = st * 16 + r16;
#pragma unroll
            for (int q = 0; q < 4; ++q) {
                int t = tb + koct * 4 + q;
                float v = (s <= t) ? acc[st][q] * 0.25f : 0.f;
                acc[st][q] = v;
                mx[q] = fmaxf(mx[q], v);
            }
        }
#pragma unroll
        for (int off = 1; off < 16; off <<= 1)
#pragma unroll
            for (int q = 0; q < 4; ++q) mx[q] = fmaxf(mx[q], __shfl_xor(mx[q], off));
        float sm[4] = {0.f, 0.f, 0.f, 0.f};
#pragma unroll
        for (int st = 0; st < 16; ++st)
#pragma unroll
            for (int q = 0; q < 4; ++q) {
                float p = __expf(acc[st][q] - mx[q]);
                acc[st][q] = p; sm[q] += p;
            }
#pragma unroll
        for (int off = 1; off < 16; off <<= 1)
#pragma unroll
            for (int q = 0; q < 4; ++q) sm[q] += __shfl_xor(sm[q], off);
        float rs[4];
#pragma unroll
        for (int q = 0; q < 4; ++q) rs[q] = __builtin_amdgcn_rcpf(sm[q]);
        // write P (bf16, swizzled) to this wave's private LDS
#pragma unroll
        for (int st = 0; st < 16; ++st) {
            int schunk = st * 2 + (r16 >> 3), sl = r16 & 7;
#pragma unroll
            for (int q = 0; q < 4; ++q) {
                int tl = koct * 4 + q;
                pw[tl * 256 + ((schunk ^ (tl & 7)) << 3) + sl] = f2bf(acc[st][q] * rs[q]);
            }
        }
        __asm__ volatile("s_waitcnt lgkmcnt(0)" ::: "memory");
        // O = P V : 8 k-steps x 2 n-tiles
        f32x4 oa[2];
        oa[0] = (f32x4){0.f, 0.f, 0.f, 0.f};
        oa[1] = (f32x4){0.f, 0.f, 0.f, 0.f};
#pragma unroll
        for (int ks = 0; ks < 8; ++ks) {
            int kc = ks * 4 + koct;
            bf16x8 pa = *(const bf16x8*)&pw[r16 * 256 + ((kc ^ (r16 & 7)) << 3)];
#pragma unroll
            for (int n = 0; n < 2; ++n) {
                int row = n * 16 + r16;
                bf16x8 vf = *(const bf16x8*)&vt_sw[row * 256 + ((kc ^ (row & 7)) << 3)];
                oa[n] = __builtin_amdgcn_mfma_f32_16x16x32_bf16(pa, vf, oa[n], 0, 0, 0);
            }
        }
#pragma unroll
        for (int n = 0; n < 2; ++n)
#pragma unroll
            for (int q = 0; q < 4; ++q)
                wvout[((size_t)b * 256 + tb + koct * 4 + q) * 32 + n * 16 + r16] = oa[n][q];
    }
}

// ---------------------------------------------------------------------------
// Kernel 5: LN2 + complex linear + LN3 + PReLU + residual (unchanged)
// ---------------------------------------------------------------------------
__global__ __launch_bounds__(256) void k_post(const float* __restrict__ wv,
                                              const float* __restrict__ in,
                                              const float* __restrict__ g2,
                                              const float* __restrict__ b2,
                                              const float* __restrict__ Wr,
                                              const float* __restrict__ br,
                                              const float* __restrict__ Wi,
                                              const float* __restrict__ bi,
                                              const float* __restrict__ g3,
                                              const float* __restrict__ b3,
                                              const float* __restrict__ pa,
                                              float* __restrict__ outp) {
    __shared__ float xv[32][33];
    __shared__ float wr_l[64][17], wi_l[64][17];
    __shared__ float out_s[64][65];
    const int tid = threadIdx.x;
    const int n = blockIdx.z, f = blockIdx.y, t0 = blockIdx.x * 32;
    const int b = n * 256 + f;
    for (int idx = tid; idx < 1024; idx += 256) {
        int dt = idx >> 5, j = idx & 31;
        xv[dt][j] = wv[((size_t)b * 256 + t0 + dt) * 32 + j];
        int cc = idx >> 4, jjj = idx & 15;
        wr_l[cc][jjj] = Wr[idx];
        wi_l[cc][jjj] = Wi[idx];
    }
    __syncthreads();
    const int lane = tid & 63, w = tid >> 6;
#pragma unroll 1
    for (int r = 0; r < 4; ++r) {
        int dt = w * 8 + r * 2 + (lane >> 5);
        int j = lane & 31;
        float v = xv[dt][j];
        float mean = hredsum(v) * 0.03125f;
        float d = v - mean;
        float var = hredsum(d * d) * 0.03125f;
        float inv = __builtin_amdgcn_rsqf(var + 1e-5f);
        xv[dt][j] = d * inv * g2[j] + b2[j];
    }
    __syncthreads();
    const int c = lane;
    const float g3c = g3[c], b3c = b3[c];
    const float bd = br[c] - bi[c], bsum = br[c] + bi[c];
    const float alpha = pa[0];
#pragma unroll 1
    for (int r = 0; r < 8; ++r) {
        int dt = w * 8 + r;
        float re = 0.f, im = 0.f;
#pragma unroll
        for (int j = 0; j < 16; ++j) {
            float xr = xv[dt][j], xi2 = xv[dt][16 + j];
            float wrv = wr_l[c][j], wiv = wi_l[c][j];
            re += xr * wrv; re -= xi2 * wiv;
            im += xi2 * wrv; im += xr * wiv;
        }
        re += bd; im += bsum;
        float mR = wredsum(re) * 0.015625f;
        float dR = re - mR;
        float vR = wredsum(dR * dR) * 0.015625f;
        float nR = dR * __builtin_amdgcn_rsqf(vR + 1e-5f) * g3c + b3c;
        nR = (nR >= 0.f) ? nR : alpha * nR;
        float mI = wredsum(im) * 0.015625f;
        float dI = im - mI;
        float vI = wredsum(dI * dI) * 0.015625f;
        float nI = dI * __builtin_amdgcn_rsqf(vI + 1e-5f) * g3c + b3c;
        nI = (nI >= 0.f) ? nI : alpha * nI;
        out_s[c][dt * 2]     = nR;
        out_s[c][dt * 2 + 1] = nI;
    }
    __syncthreads();
    const int cc = tid >> 2, q = tid & 3;
    size_t base = ((size_t)(n * 64 + cc) * 256 + f) * 512 + t0 * 2 + q * 16;
#pragma unroll
    for (int e = 0; e < 4; ++e) {
        float4 iv = *(const float4*)(in + base + e * 4);
        int k0 = q * 16 + e * 4;
        float4 ov;
        ov.x = out_s[cc][k0]     + iv.x;
        ov.y = out_s[cc][k0 + 1] + iv.y;
        ov.z = out_s[cc][k0 + 2] + iv.z;
        ov.w = out_s[cc][k0 + 3] + iv.w;
        *(float4*)(outp + base + e * 4) = ov;
    }
}

// ---------------------------------------------------------------------------
extern "C" void kernel_launch(void* const* d_in, const int* in_sizes, int n_in,
                              void* d_out, int out_size, void* d_ws, size_t ws_size,
                              hipStream_t stream) {
    const float* in   = (const float*)d_in[0];
    const float* g1   = (const float*)d_in[1];
    const float* b1   = (const float*)d_in[2];
    const float* Wq   = (const float*)d_in[3];
    const float* Whq  = (const float*)d_in[4];
    const float* bihq = (const float*)d_in[5];
    const float* bhhq = (const float*)d_in[6];
    const float* Wk   = (const float*)d_in[7];
    const float* Whk  = (const float*)d_in[8];
    const float* bihk = (const float*)d_in[9];
    const float* bhhk = (const float*)d_in[10];
    const float* Wv   = (const float*)d_in[11];
    const float* Whv  = (const float*)d_in[12];
    const float* bihv = (const float*)d_in[13];
    const float* bhhv = (const float*)d_in[14];
    const float* g2   = (const float*)d_in[15];
    const float* b2   = (const float*)d_in[16];
    const float* Wr   = (const float*)d_in[17];
    const float* br   = (const float*)d_in[18];
    const float* Wi   = (const float*)d_in[19];
    const float* bi   = (const float*)d_in[20];
    const float* g3   = (const float*)d_in[21];
    const float* b3   = (const float*)d_in[22];
    const float* pa   = (const float*)d_in[23];
    float* outp = (float*)d_out;

    // workspace layout (bytes):
    // [0, 201326592)            gx  bf16  262144*384*2
    // [201326592, 268435456)    xn  bf16  262144*128*2
    // [268435456, 318767104)    qkv bf16  3*262144*32*2
    // [318767104, 352321536)    wv  fp32  262144*32*4
    ushort* gxb  = (ushort*)d_ws;
    ushort* xnb  = (ushort*)((char*)d_ws + 201326592);
    ushort* qkvb = (ushort*)((char*)d_ws + 268435456);
    float*  wvb  = (float*)((char*)d_ws + 318767104);

    k_prep<<<dim3(8, 256, 4), dim3(256), 0, stream>>>(in, g1, b1, xnb);
    k_gemm<<<dim3(2048, 6), dim3(256), 0, stream>>>(xnb, Wq, Wk, Wv,
                                                    bihq, bhhq, bihk, bhhk, bihv, bhhv, gxb);
    k_lstm<<<dim3(768), dim3(256), 0, stream>>>(gxb, Whq, Whk, Whv, qkvb);
    k_attn<<<dim3(1024), dim3(256), 0, stream>>>(qkvb, wvb);
    k_post<<<dim3(8, 256, 4), dim3(256), 0, stream>>>(wvb, in, g2, b2,
                                                      Wr, br, Wi, bi, g3, b3, pa, outp);
}